// Round 3
// baseline (18.994 us; speedup 1.0000x reference)
//
#include <hip/hip_runtime.h>

// BKT: B=4096 students, T=512 timesteps, K=2048 skills.
// One block per student, one thread per timestep.
// Round-based propagation: build per-skill linked lists (unordered, LDS
// atomicExch), one chain walk to find prev/rank, then maxrank rounds where
// rank-r threads read their predecessor's published posterior and publish
// their own. Critical path: O(L) LDS hops + O(maxrank) barriers.
// R2 bug fixed: maxrank must be bumped for rank >= 1 (was rank > 1, which
// dropped blocks whose longest chain is exactly 2 -> rank-1 threads emitted
// k0; ~1.3% of blocks, absmax 0.725).

#define BKT_B 4096
#define BKT_T 512
#define BKT_K 2048

__device__ __forceinline__ float bkt_update(float pL, float r, float ss,
                                            float gg, float tt) {
  float num, den;
  if (r > 0.5f) {            // correct response
    num = pL * (1.0f - ss);
    den = num + (1.0f - pL) * gg;
  } else {                   // incorrect response
    num = pL * ss;
    den = num + (1.0f - pL) * (1.0f - gg);
  }
  const float q = num / den; // Bayesian posterior
  return q + (1.0f - q) * tt;// learning transition
}

__global__ __launch_bounds__(512) void bkt_kernel(
    const int* __restrict__ skills,
    const float* __restrict__ resp,
    const float* __restrict__ k0,
    const float* __restrict__ tp,
    const float* __restrict__ gp,
    const float* __restrict__ sp,
    float* __restrict__ out) {
  __shared__ int   nxt_s[BKT_T];    // linked-list next (arbitrary order)
  __shared__ float resp_s[BKT_T];
  __shared__ float post_s[BKT_T];   // posterior AFTER update at time t
  __shared__ int   head_s[BKT_K];   // per-skill list head
  __shared__ int   maxrank_s;

  const int b = blockIdx.x;
  const int t = threadIdx.x;
  const int base = b * BKT_T;

  const int sk = skills[base + t];
  resp_s[t] = resp[base + t];
  if (t == 0) maxrank_s = 0;
#pragma unroll
  for (int i = 0; i < BKT_K / BKT_T; ++i)
    head_s[t + i * BKT_T] = -1;
  __syncthreads();

  // build per-skill linked lists (order irrelevant)
  nxt_s[t] = atomicExch(&head_s[sk], t);
  __syncthreads();

  // single chain walk: prev = latest earlier same-skill touch, rank = count
  int prev = -1, rank = 0;
  for (int j = head_s[sk]; j >= 0; j = nxt_s[j]) {
    if (j < t) { ++rank; prev = max(prev, j); }
  }
  if (rank >= 1) atomicMax(&maxrank_s, rank);

  // per-skill params (8 KB tables, L1/L2 resident)
  const float ss = sp[sk];
  const float gg = gp[sk];
  const float tt = tp[sk];
  const float rr = resp_s[t];
  float pL = k0[sk];               // mastery BEFORE update at t (rank 0)

  if (rank == 0) post_s[t] = bkt_update(pL, rr, ss, gg, tt);
  __syncthreads();

  const int MR = maxrank_s;
  for (int rd = 1; rd <= MR; ++rd) {
    if (rank == rd) {
      pL = post_s[prev];
      post_s[t] = bkt_update(pL, rr, ss, gg, tt);
    }
    __syncthreads();
  }

  out[base + t] = pL;              // emit pre-update mastery
}

extern "C" void kernel_launch(void* const* d_in, const int* in_sizes, int n_in,
                              void* d_out, int out_size, void* d_ws, size_t ws_size,
                              hipStream_t stream) {
  const int*   skills = (const int*)d_in[0];
  const float* resp   = (const float*)d_in[1];
  const float* k0     = (const float*)d_in[2];
  const float* tp     = (const float*)d_in[3];
  const float* gp     = (const float*)d_in[4];
  const float* sp     = (const float*)d_in[5];
  float* out = (float*)d_out;

  bkt_kernel<<<BKT_B, BKT_T, 0, stream>>>(skills, resp, k0, tp, gp, sp, out);
}